// Round 1
// baseline (7054.907 us; speedup 1.0000x reference)
//
#include <hip/hip_runtime.h>
#include <math.h>

// Dims (fixed by the problem)
#define BB 8
#define SS 512
#define DD 512
#define HH 8
#define HSD 64
#define FFD 2048
#define LL 6
#define VV 1024
#define NROWS (BB*SS)          // 4096
#define EPS 1e-5f

// ---------------------------------------------------------------------------
// Embed: x[n,d] = emb[idx(n),d]*sqrt(D) + pe(s,d)
// tokens is exactly one-hot, so the matmul is an exact gather.
// pe[s,i] = sin/cos( s / 10000^(2i/512) )   (exponent uses seq_len=512!)
// ---------------------------------------------------------------------------
__global__ __launch_bounds__(256)
void embed_kernel(const float* __restrict__ tokens,
                  const float* __restrict__ emb,
                  float* __restrict__ x)
{
    const int n = blockIdx.x;            // 0..4095
    const int s = n & (SS - 1);
    const int t = threadIdx.x;
    __shared__ int sidx;
    #pragma unroll
    for (int r = 0; r < 4; ++r) {
        int v = t + 256 * r;
        if (tokens[(long)n * VV + v] > 0.5f) sidx = v;
    }
    __syncthreads();
    const int idx = sidx;
    const float sq = 22.62741699796952f; // sqrt(512)
    #pragma unroll
    for (int r = 0; r < 2; ++r) {
        int d = t + 256 * r;
        float e = emb[(long)idx * DD + d] * sq;
        float expo  = (2.0f * (float)d) / 512.0f;
        float denom = powf(10000.0f, expo);
        float val   = (float)s / denom;
        float pe = ((d & 1) == 0) ? sinf(val) : cosf(val);
        x[(long)n * DD + d] = e + pe;
    }
}

// ---------------------------------------------------------------------------
// Generic fp32 GEMM: C[M,N]=A[M,K]@B[K,N] (or B[N,K] if BT), 64x64x16 tiles,
// 256 threads, 4x4 microtile. Batched over gridDim.z (per-head QKV).
// Epilogue: +bias, relu, +residual.
// Requires M%64==0, N%64==0 (per batch), K%16==0.
// ---------------------------------------------------------------------------
template<bool BT, bool BIAS, bool RELU, bool RES>
__global__ __launch_bounds__(256)
void gemm_kernel(const float* __restrict__ A, const float* __restrict__ B,
                 const float* __restrict__ bias, const float* __restrict__ res,
                 float* __restrict__ C,
                 int M, int N, int K, int lda, int ldb, int ldc,
                 long bStrideB, int bStrideBias, int bColOff)
{
    const int t  = threadIdx.x;
    const int bm = blockIdx.y * 64;
    const int bn = blockIdx.x * 64;
    const int bz = blockIdx.z;
    const float* Bp = B + (long)bz * bStrideB;
    const int colOff = bz * bColOff;

    __shared__ float As[16][65];
    __shared__ float Bs[16][65];

    const int ar = t >> 2;            // 0..63 (row within tile)
    const int ac = (t & 3) * 4;       // 0,4,8,12 (k group)
    const int tm = (t & 15) * 4;
    const int tn = (t >> 4) * 4;

    float acc[4][4] = {};

    for (int k0 = 0; k0 < K; k0 += 16) {
        float4 av = *(const float4*)(A + (long)(bm + ar) * lda + k0 + ac);
        As[ac + 0][ar] = av.x; As[ac + 1][ar] = av.y;
        As[ac + 2][ar] = av.z; As[ac + 3][ar] = av.w;
        if (!BT) {
            int br = t >> 4;              // 0..15 (k row)
            int bc = (t & 15) * 4;        // col group
            float4 bv = *(const float4*)(Bp + (long)(k0 + br) * ldb + bn + bc);
            Bs[br][bc + 0] = bv.x; Bs[br][bc + 1] = bv.y;
            Bs[br][bc + 2] = bv.z; Bs[br][bc + 3] = bv.w;
        } else {
            float4 bv = *(const float4*)(Bp + (long)(bn + ar) * ldb + k0 + ac);
            Bs[ac + 0][ar] = bv.x; Bs[ac + 1][ar] = bv.y;
            Bs[ac + 2][ar] = bv.z; Bs[ac + 3][ar] = bv.w;
        }
        __syncthreads();
        #pragma unroll
        for (int kk = 0; kk < 16; ++kk) {
            float a[4], b[4];
            #pragma unroll
            for (int u = 0; u < 4; ++u) { a[u] = As[kk][tm + u]; b[u] = Bs[kk][tn + u]; }
            #pragma unroll
            for (int ii = 0; ii < 4; ++ii)
                #pragma unroll
                for (int jj = 0; jj < 4; ++jj)
                    acc[ii][jj] += a[ii] * b[jj];
        }
        __syncthreads();
    }

    #pragma unroll
    for (int ii = 0; ii < 4; ++ii) {
        int r = bm + tm + ii;
        #pragma unroll
        for (int jj = 0; jj < 4; ++jj) {
            int c = bn + tn + jj;
            float v = acc[ii][jj];
            if (BIAS) v += bias[(long)bz * bStrideBias + c];
            if (RELU) v = fmaxf(v, 0.0f);
            int gc = colOff + c;
            if (RES) v += res[(long)r * ldc + gc];
            C[(long)r * ldc + gc] = v;
        }
    }
}

// ---------------------------------------------------------------------------
// Attention: one wave (64 threads) per (b,h,i) row.
// qkv layout: [n=b*512+s][h][192]  (q:0..63, k:64..127, v:128..191), row stride 1536.
// z[j] = 0 for j<=i ; (logit * -1e6) * 0.125 for j>i.  softmax w/ max-subtract.
// Output written directly in concat layout oc[n][h*64+k].
// ---------------------------------------------------------------------------
__global__ __launch_bounds__(64)
void attn_kernel(const float* __restrict__ qkv, float* __restrict__ oc)
{
    const int i = blockIdx.x, h = blockIdx.y, b = blockIdx.z;
    const int t = threadIdx.x;
    __shared__ float qs[64];
    __shared__ float attn_s[512];

    const long bhBase = (long)b * SS * 1536 + (long)h * 192;
    qs[t] = qkv[bhBase + (long)i * 1536 + t];
    __syncthreads();

    const float4* qs4 = (const float4*)qs;
    float p[8];
    float mx = -3.4e38f;
    #pragma unroll
    for (int r = 0; r < 8; ++r) {
        int j = r * 64 + t;
        const float4* krow = (const float4*)(qkv + bhBase + (long)j * 1536 + 64);
        float dot = 0.0f;
        #pragma unroll
        for (int kk = 0; kk < 16; ++kk) {
            float4 kv = krow[kk];
            float4 qq = qs4[kk];
            dot += qq.x * kv.x + qq.y * kv.y + qq.z * kv.z + qq.w * kv.w;
        }
        float z = (j <= i) ? 0.0f : (dot * -1.0e6f) * 0.125f;
        p[r] = z;
        mx = fmaxf(mx, z);
    }
    #pragma unroll
    for (int o = 32; o >= 1; o >>= 1) mx = fmaxf(mx, __shfl_xor(mx, o));
    float sum = 0.0f;
    #pragma unroll
    for (int r = 0; r < 8; ++r) { p[r] = expf(p[r] - mx); sum += p[r]; }
    #pragma unroll
    for (int o = 32; o >= 1; o >>= 1) sum += __shfl_xor(sum, o);
    const float inv = 1.0f / sum;
    #pragma unroll
    for (int r = 0; r < 8; ++r) attn_s[r * 64 + t] = p[r] * inv;
    __syncthreads();

    float o = 0.0f;
    const float* vbase = qkv + bhBase + 128;
    for (int j = 0; j < 512; ++j)
        o += attn_s[j] * vbase[(long)j * 1536 + t];
    oc[((long)(b * SS + i)) * DD + h * HSD + t] = o;
}

// ---------------------------------------------------------------------------
// LayerNorm over rows of 512; block = 256 threads (2 elems each).
// ---------------------------------------------------------------------------
__device__ __forceinline__ float blk_sum(float v, float* sb)
{
    #pragma unroll
    for (int m = 32; m >= 1; m >>= 1) v += __shfl_xor(v, m);
    if ((threadIdx.x & 63) == 0) sb[threadIdx.x >> 6] = v;
    __syncthreads();
    v = sb[0] + sb[1] + sb[2] + sb[3];
    __syncthreads();
    return v;
}

__global__ __launch_bounds__(256)
void ln_kernel(const float* __restrict__ in, const float* __restrict__ g,
               const float* __restrict__ bb, float* __restrict__ out)
{
    __shared__ float sb[4];
    const int n = blockIdx.x;
    const int t = threadIdx.x;
    const float* x = in + (long)n * DD;
    float v0 = x[t], v1 = x[t + 256];
    float total = blk_sum(v0 + v1, sb);
    float mean = total * (1.0f / 512.0f);
    float d0 = v0 - mean, d1 = v1 - mean;
    float ss = blk_sum(d0 * d0 + d1 * d1, sb);
    float var = ss * (1.0f / 512.0f);
    float inv = 1.0f / sqrtf(var + EPS);
    out[(long)n * DD + t]       = d0 * inv * g[t]       + bb[t];
    out[(long)n * DD + t + 256] = d1 * inv * g[t + 256] + bb[t + 256];
}

// ---------------------------------------------------------------------------
extern "C" void kernel_launch(void* const* d_in, const int* in_sizes, int n_in,
                              void* d_out, int out_size, void* d_ws, size_t ws_size,
                              hipStream_t stream)
{
    const float* tokens = (const float*)d_in[0];
    const float* emb    = (const float*)d_in[1];
    const float* qkv_w  = (const float*)d_in[2];
    const float* qkv_b  = (const float*)d_in[3];
    const float* out_w  = (const float*)d_in[4];
    const float* out_b  = (const float*)d_in[5];
    const float* w1     = (const float*)d_in[6];
    const float* b1     = (const float*)d_in[7];
    const float* w2     = (const float*)d_in[8];
    const float* b2     = (const float*)d_in[9];
    const float* ln1_g  = (const float*)d_in[10];
    const float* ln1_b  = (const float*)d_in[11];
    const float* ln2_g  = (const float*)d_in[12];
    const float* ln2_b  = (const float*)d_in[13];
    float* out = (float*)d_out;

    float* ws  = (float*)d_ws;
    float* x   = ws;                          // [4096,512]
    float* y   = x  + (long)NROWS * DD;       // [4096,512]
    float* oc  = y  + (long)NROWS * DD;       // [4096,512]
    float* big = oc + (long)NROWS * DD;       // [4096,2048] (qkv OR ffn hidden)

    embed_kernel<<<NROWS, 256, 0, stream>>>(tokens, emb, x);

    for (int l = 0; l < LL; ++l) {
        const float* qw  = qkv_w + (long)l * HH * DD * 192;
        const float* qb  = qkv_b + (long)l * HH * 192;
        const float* ow  = out_w + (long)l * DD * DD;
        const float* ob  = out_b + (long)l * DD;
        const float* w1l = w1 + (long)l * DD * FFD;
        const float* b1l = b1 + (long)l * FFD;
        const float* w2l = w2 + (long)l * FFD * DD;
        const float* b2l = b2 + (long)l * DD;

        // QKV: per-head batched GEMM [4096,512]@[512,192] -> big[n][h][192]
        gemm_kernel<false, true, false, false><<<dim3(3, 64, 8), 256, 0, stream>>>(
            x, qw, qb, nullptr, big,
            NROWS, 192, DD, DD, 192, 1536,
            (long)DD * 192, 192, 192);

        attn_kernel<<<dim3(SS, HH, BB), 64, 0, stream>>>(big, oc);

        // out-proj + bias + residual(x) -> y
        gemm_kernel<false, true, false, true><<<dim3(8, 64, 1), 256, 0, stream>>>(
            oc, ow, ob, x, y,
            NROWS, DD, DD, DD, DD, DD, 0, 0, 0);

        ln_kernel<<<NROWS, 256, 0, stream>>>(y, ln1_g + (long)l * DD, ln1_b + (long)l * DD, x);

        // FFN1 + relu -> big
        gemm_kernel<false, true, true, false><<<dim3(32, 64, 1), 256, 0, stream>>>(
            x, w1l, b1l, nullptr, big,
            NROWS, FFD, DD, DD, FFD, FFD, 0, 0, 0);

        // FFN2 + bias + residual(x) -> y
        gemm_kernel<false, true, false, true><<<dim3(8, 64, 1), 256, 0, stream>>>(
            big, w2l, b2l, x, y,
            NROWS, DD, FFD, FFD, DD, DD, 0, 0, 0);

        ln_kernel<<<NROWS, 256, 0, stream>>>(y, ln2_g + (long)l * DD, ln2_b + (long)l * DD, x);
    }

    // final: out = x @ emb^T   (NT GEMM, [4096,512]@[1024,512]^T)
    gemm_kernel<true, false, false, false><<<dim3(16, 64, 1), 256, 0, stream>>>(
        x, emb, nullptr, nullptr, out,
        NROWS, VV, DD, DD, DD, VV, 0, 0, 0);
}

// Round 4
// 6260.504 us; speedup vs baseline: 1.1269x; 1.1269x over previous
//
#include <hip/hip_runtime.h>
#include <math.h>

// Dims (fixed by the problem)
#define BB 8
#define SS 512
#define DD 512
#define HH 8
#define HSD 64
#define FFD 2048
#define LL 6
#define VV 1024
#define NROWS (BB*SS)          // 4096
#define EPS 1e-5f

// ---------------------------------------------------------------------------
// Embed (unchanged from R1 — passing config)
// ---------------------------------------------------------------------------
__global__ __launch_bounds__(256)
void embed_kernel(const float* __restrict__ tokens,
                  const float* __restrict__ emb,
                  float* __restrict__ x)
{
    const int n = blockIdx.x;            // 0..4095
    const int s = n & (SS - 1);
    const int t = threadIdx.x;
    __shared__ int sidx;
    #pragma unroll
    for (int r = 0; r < 4; ++r) {
        int v = t + 256 * r;
        if (tokens[(long)n * VV + v] > 0.5f) sidx = v;
    }
    __syncthreads();
    const int idx = sidx;
    const float sq = 22.62741699796952f; // sqrt(512)
    #pragma unroll
    for (int r = 0; r < 2; ++r) {
        int d = t + 256 * r;
        float e = emb[(long)idx * DD + d] * sq;
        float expo  = (2.0f * (float)d) / 512.0f;
        float denom = powf(10000.0f, expo);
        float val   = (float)s / denom;
        float pe = ((d & 1) == 0) ? sinf(val) : cosf(val);
        x[(long)n * DD + d] = e + pe;
    }
}

// ---------------------------------------------------------------------------
// Old 64x64 GEMM (unchanged from R1) — kept for QKV (N=192 per head).
// ---------------------------------------------------------------------------
template<bool BT, bool BIAS, bool RELU, bool RES>
__global__ __launch_bounds__(256)
void gemm_kernel(const float* __restrict__ A, const float* __restrict__ B,
                 const float* __restrict__ bias, const float* __restrict__ res,
                 float* __restrict__ C,
                 int M, int N, int K, int lda, int ldb, int ldc,
                 long bStrideB, int bStrideBias, int bColOff)
{
    const int t  = threadIdx.x;
    const int bm = blockIdx.y * 64;
    const int bn = blockIdx.x * 64;
    const int bz = blockIdx.z;
    const float* Bp = B + (long)bz * bStrideB;
    const int colOff = bz * bColOff;

    __shared__ float As[16][65];
    __shared__ float Bs[16][65];

    const int ar = t >> 2;
    const int ac = (t & 3) * 4;
    const int tm = (t & 15) * 4;
    const int tn = (t >> 4) * 4;

    float acc[4][4] = {};

    for (int k0 = 0; k0 < K; k0 += 16) {
        float4 av = *(const float4*)(A + (long)(bm + ar) * lda + k0 + ac);
        As[ac + 0][ar] = av.x; As[ac + 1][ar] = av.y;
        As[ac + 2][ar] = av.z; As[ac + 3][ar] = av.w;
        if (!BT) {
            int br = t >> 4;
            int bc = (t & 15) * 4;
            float4 bv = *(const float4*)(Bp + (long)(k0 + br) * ldb + bn + bc);
            Bs[br][bc + 0] = bv.x; Bs[br][bc + 1] = bv.y;
            Bs[br][bc + 2] = bv.z; Bs[br][bc + 3] = bv.w;
        } else {
            float4 bv = *(const float4*)(Bp + (long)(bn + ar) * ldb + k0 + ac);
            Bs[ac + 0][ar] = bv.x; Bs[ac + 1][ar] = bv.y;
            Bs[ac + 2][ar] = bv.z; Bs[ac + 3][ar] = bv.w;
        }
        __syncthreads();
        #pragma unroll
        for (int kk = 0; kk < 16; ++kk) {
            float a[4], b[4];
            #pragma unroll
            for (int u = 0; u < 4; ++u) { a[u] = As[kk][tm + u]; b[u] = Bs[kk][tn + u]; }
            #pragma unroll
            for (int ii = 0; ii < 4; ++ii)
                #pragma unroll
                for (int jj = 0; jj < 4; ++jj)
                    acc[ii][jj] += a[ii] * b[jj];
        }
        __syncthreads();
    }

    #pragma unroll
    for (int ii = 0; ii < 4; ++ii) {
        int r = bm + tm + ii;
        #pragma unroll
        for (int jj = 0; jj < 4; ++jj) {
            int c = bn + tn + jj;
            float v = acc[ii][jj];
            if (BIAS) v += bias[(long)bz * bStrideBias + c];
            if (RELU) v = fmaxf(v, 0.0f);
            int gc = colOff + c;
            if (RES) v += res[(long)r * ldc + gc];
            C[(long)r * ldc + gc] = v;
        }
    }
}

// ---------------------------------------------------------------------------
// 128x128x16 GEMM, 8x8 microtile. BK=16 + single-fmac-per-k keeps the
// per-element accumulation order BITWISE IDENTICAL to gemm_kernel (the
// winner-selection-critical attention logits depend on upstream bits).
// ---------------------------------------------------------------------------
template<bool BT, bool BIAS, bool RELU, bool RES>
__global__ __launch_bounds__(256)
void gemm128_kernel(const float* __restrict__ A, const float* __restrict__ B,
                    const float* __restrict__ bias, const float* __restrict__ res,
                    float* __restrict__ C,
                    int M, int N, int K, int lda, int ldb, int ldc)
{
    const int t  = threadIdx.x;
    const int bm = blockIdx.y * 128;
    const int bn = blockIdx.x * 128;
    __shared__ float As[16][132];
    __shared__ float Bs[16][132];
    const int tx = t & 15;         // output col group (tx*8)
    const int ty = t >> 4;         // output row group (ty*8)
    float acc[8][8] = {};

    for (int k0 = 0; k0 < K; k0 += 16) {
        #pragma unroll
        for (int p = 0; p < 2; ++p) {   // A: 128x16 -> As[k][m] (transposed)
            int q = t + 256 * p;        // 0..511
            int r = q >> 2, kc = (q & 3) * 4;
            float4 a4 = *(const float4*)(A + (long)(bm + r) * lda + k0 + kc);
            As[kc + 0][r] = a4.x; As[kc + 1][r] = a4.y;
            As[kc + 2][r] = a4.z; As[kc + 3][r] = a4.w;
        }
        if (!BT) {
            #pragma unroll
            for (int p = 0; p < 2; ++p) {   // B: 16x128 row-major
                int q = t + 256 * p;
                int r = q >> 5, c = (q & 31) * 4;
                *(float4*)&Bs[r][c] = *(const float4*)(B + (long)(k0 + r) * ldb + bn + c);
            }
        } else {
            #pragma unroll
            for (int p = 0; p < 2; ++p) {   // B^T: 128 rows x 16 k -> Bs[k][n]
                int q = t + 256 * p;
                int r = q >> 2, kc = (q & 3) * 4;
                float4 b4 = *(const float4*)(B + (long)(bn + r) * ldb + k0 + kc);
                Bs[kc + 0][r] = b4.x; Bs[kc + 1][r] = b4.y;
                Bs[kc + 2][r] = b4.z; Bs[kc + 3][r] = b4.w;
            }
        }
        __syncthreads();
        #pragma unroll
        for (int kk = 0; kk < 16; ++kk) {
            float a[8], bv[8];
            *(float4*)&a[0]  = *(const float4*)&As[kk][ty * 8];
            *(float4*)&a[4]  = *(const float4*)&As[kk][ty * 8 + 4];
            *(float4*)&bv[0] = *(const float4*)&Bs[kk][tx * 8];
            *(float4*)&bv[4] = *(const float4*)&Bs[kk][tx * 8 + 4];
            #pragma unroll
            for (int ii = 0; ii < 8; ++ii)
                #pragma unroll
                for (int jj = 0; jj < 8; ++jj)
                    acc[ii][jj] += a[ii] * bv[jj];
        }
        __syncthreads();
    }

    #pragma unroll
    for (int ii = 0; ii < 8; ++ii) {
        int r = bm + ty * 8 + ii;
        #pragma unroll
        for (int jj = 0; jj < 8; ++jj) {
            int c = bn + tx * 8 + jj;
            float v = acc[ii][jj];
            if (BIAS) v += bias[c];
            if (RELU) v = fmaxf(v, 0.0f);
            if (RES)  v += res[(long)r * ldc + c];
            C[(long)r * ldc + c] = v;
        }
    }
}

// ---------------------------------------------------------------------------
// Attention v3: exact softmax, BITWISE-identical math to the R1 kernel that
// passed (dot expression, j->lane mapping, max/exp/sum butterflies, P
// normalization, sequential-j PV chain all preserved verbatim), but executed
// as: 256-thread block per (b,h,16 Q rows), K/V tiles staged in LDS
// (coalesced), z row buffer in LDS, 4 waves each owning 4 rows.
// qkv layout: [n][h][192] (q:0..63,k:64..127,v:128..191), row stride 1536.
// ---------------------------------------------------------------------------
__global__ __launch_bounds__(256)
void attn_kernel(const float* __restrict__ qkv, float* __restrict__ oc)
{
    const int i0 = blockIdx.x * 16;
    const int h  = blockIdx.y, b = blockIdx.z;
    const int t  = threadIdx.x;
    const int w  = t >> 6;               // wave 0..3 -> rows 4w..4w+3
    const int ln = t & 63;               // lane -> j offset / output d

    __shared__ float Qs[16][68];         // Q rows
    __shared__ float KVs[64][68];        // K tile (pass1), V^T tile (pass2)
    __shared__ float Zb[16][512];        // z, then P

    const long bhBase = (long)b * SS * 1536 + (long)h * 192;

    {   // stage Q: 16 rows x 64, one float4/thread
        int r = t >> 4, c = (t & 15) * 4;
        *(float4*)&Qs[r][c] =
            *(const float4*)(qkv + bhBase + (long)(i0 + r) * 1536 + c);
    }
    __syncthreads();

    // ---- pass 1: scores ----
    for (int kt = 0; kt < 8; ++kt) {
        const int j0 = kt * 64;
        #pragma unroll
        for (int p = 0; p < 4; ++p) {    // K tile 64x64 row-major
            int q = t + 256 * p;         // 0..1023
            int r = q >> 4, c = (q & 15) * 4;
            *(float4*)&KVs[r][c] =
                *(const float4*)(qkv + bhBase + (long)(j0 + r) * 1536 + 64 + c);
        }
        __syncthreads();

        const float4* k4 = (const float4*)&KVs[ln][0];
        #pragma unroll
        for (int c = 0; c < 4; ++c) {
            const int i = 4 * w + c;
            const float4* q4 = (const float4*)&Qs[i][0];
            float dot = 0.0f;
            #pragma unroll
            for (int kk = 0; kk < 16; ++kk) {
                float4 kv = k4[kk];
                float4 qq = q4[kk];
                dot += qq.x * kv.x + qq.y * kv.y + qq.z * kv.z + qq.w * kv.w;
            }
            const int gi = i0 + i, gj = j0 + ln;
            Zb[i][j0 + ln] = (gj <= gi) ? 0.0f : (dot * -1.0e6f) * 0.125f;
        }
        __syncthreads();
    }

    // ---- softmax (each wave: its 4 rows; R1-verbatim reductions) ----
    #pragma unroll
    for (int c = 0; c < 4; ++c) {
        const int i = 4 * w + c;
        float p[8];
        float mx = -3.4e38f;
        #pragma unroll
        for (int r = 0; r < 8; ++r) { p[r] = Zb[i][r * 64 + ln]; mx = fmaxf(mx, p[r]); }
        #pragma unroll
        for (int o = 32; o >= 1; o >>= 1) mx = fmaxf(mx, __shfl_xor(mx, o));
        float sum = 0.0f;
        #pragma unroll
        for (int r = 0; r < 8; ++r) { p[r] = expf(p[r] - mx); sum += p[r]; }
        #pragma unroll
        for (int o = 32; o >= 1; o >>= 1) sum += __shfl_xor(sum, o);
        const float inv = 1.0f / sum;
        #pragma unroll
        for (int r = 0; r < 8; ++r) Zb[i][r * 64 + ln] = p[r] * inv;
    }
    __syncthreads();

    // ---- pass 2: O = P V, sequential-j fmac chain (R1 order) ----
    float oA[4] = {0.0f, 0.0f, 0.0f, 0.0f};
    for (int kt = 0; kt < 8; ++kt) {
        const int j0 = kt * 64;
        #pragma unroll
        for (int p = 0; p < 4; ++p) {    // V tile staged TRANSPOSED: KVs[d][j]
            int q = t + 256 * p;
            int r = q >> 4, c = (q & 15) * 4;
            float4 v4 = *(const float4*)(qkv + bhBase + (long)(j0 + r) * 1536 + 128 + c);
            KVs[c + 0][r] = v4.x; KVs[c + 1][r] = v4.y;
            KVs[c + 2][r] = v4.z; KVs[c + 3][r] = v4.w;
        }
        __syncthreads();

        const float4* vt = (const float4*)&KVs[ln][0];   // V^T row d=ln
        #pragma unroll
        for (int c = 0; c < 4; ++c) {
            const int i = 4 * w + c;
            const float4* pr = (const float4*)&Zb[i][j0];
            float acc = oA[c];
            #pragma unroll
            for (int kk = 0; kk < 16; ++kk) {
                float4 pv = pr[kk];
                float4 vv = vt[kk];
                acc += pv.x * vv.x;
                acc += pv.y * vv.y;
                acc += pv.z * vv.z;
                acc += pv.w * vv.w;
            }
            oA[c] = acc;
        }
        __syncthreads();
    }

    // epilogue: concat-head layout oc[n][h*64 + d], d = lane (coalesced)
    #pragma unroll
    for (int c = 0; c < 4; ++c) {
        const int gi = i0 + 4 * w + c;
        oc[(long)(b * SS + gi) * DD + h * HSD + ln] = oA[c];
    }
}

// ---------------------------------------------------------------------------
// LayerNorm (unchanged from R1)
// ---------------------------------------------------------------------------
__device__ __forceinline__ float blk_sum(float v, float* sb)
{
    #pragma unroll
    for (int m = 32; m >= 1; m >>= 1) v += __shfl_xor(v, m);
    if ((threadIdx.x & 63) == 0) sb[threadIdx.x >> 6] = v;
    __syncthreads();
    v = sb[0] + sb[1] + sb[2] + sb[3];
    __syncthreads();
    return v;
}

__global__ __launch_bounds__(256)
void ln_kernel(const float* __restrict__ in, const float* __restrict__ g,
               const float* __restrict__ bb, float* __restrict__ out)
{
    __shared__ float sb[4];
    const int n = blockIdx.x;
    const int t = threadIdx.x;
    const float* x = in + (long)n * DD;
    float v0 = x[t], v1 = x[t + 256];
    float total = blk_sum(v0 + v1, sb);
    float mean = total * (1.0f / 512.0f);
    float d0 = v0 - mean, d1 = v1 - mean;
    float ss = blk_sum(d0 * d0 + d1 * d1, sb);
    float var = ss * (1.0f / 512.0f);
    float inv = 1.0f / sqrtf(var + EPS);
    out[(long)n * DD + t]       = d0 * inv * g[t]       + bb[t];
    out[(long)n * DD + t + 256] = d1 * inv * g[t + 256] + bb[t + 256];
}

// ---------------------------------------------------------------------------
extern "C" void kernel_launch(void* const* d_in, const int* in_sizes, int n_in,
                              void* d_out, int out_size, void* d_ws, size_t ws_size,
                              hipStream_t stream)
{
    const float* tokens = (const float*)d_in[0];
    const float* emb    = (const float*)d_in[1];
    const float* qkv_w  = (const float*)d_in[2];
    const float* qkv_b  = (const float*)d_in[3];
    const float* out_w  = (const float*)d_in[4];
    const float* out_b  = (const float*)d_in[5];
    const float* w1     = (const float*)d_in[6];
    const float* b1     = (const float*)d_in[7];
    const float* w2     = (const float*)d_in[8];
    const float* b2     = (const float*)d_in[9];
    const float* ln1_g  = (const float*)d_in[10];
    const float* ln1_b  = (const float*)d_in[11];
    const float* ln2_g  = (const float*)d_in[12];
    const float* ln2_b  = (const float*)d_in[13];
    float* out = (float*)d_out;

    float* ws  = (float*)d_ws;
    float* x   = ws;                          // [4096,512]
    float* y   = x  + (long)NROWS * DD;       // [4096,512]
    float* oc  = y  + (long)NROWS * DD;       // [4096,512]
    float* big = oc + (long)NROWS * DD;       // [4096,2048]

    embed_kernel<<<NROWS, 256, 0, stream>>>(tokens, emb, x);

    for (int l = 0; l < LL; ++l) {
        const float* qw  = qkv_w + (long)l * HH * DD * 192;
        const float* qb  = qkv_b + (long)l * HH * 192;
        const float* ow  = out_w + (long)l * DD * DD;
        const float* ob  = out_b + (long)l * DD;
        const float* w1l = w1 + (long)l * DD * FFD;
        const float* b1l = b1 + (long)l * FFD;
        const float* w2l = w2 + (long)l * FFD * DD;
        const float* b2l = b2 + (long)l * DD;

        // QKV: per-head batched GEMM (old kernel, N=192) -> big[n][h][192]
        gemm_kernel<false, true, false, false><<<dim3(3, 64, 8), 256, 0, stream>>>(
            x, qw, qb, nullptr, big,
            NROWS, 192, DD, DD, 192, 1536,
            (long)DD * 192, 192, 192);

        attn_kernel<<<dim3(SS / 16, HH, BB), 256, 0, stream>>>(big, oc);

        // out-proj + bias + residual(x) -> y
        gemm128_kernel<false, true, false, true><<<dim3(4, 32), 256, 0, stream>>>(
            oc, ow, ob, x, y, NROWS, DD, DD, DD, DD, DD);

        ln_kernel<<<NROWS, 256, 0, stream>>>(y, ln1_g + (long)l * DD, ln1_b + (long)l * DD, x);

        // FFN1 + relu -> big
        gemm128_kernel<false, true, true, false><<<dim3(16, 32), 256, 0, stream>>>(
            x, w1l, b1l, nullptr, big, NROWS, FFD, DD, DD, FFD, FFD);

        // FFN2 + bias + residual(x) -> y
        gemm128_kernel<false, true, false, true><<<dim3(4, 32), 256, 0, stream>>>(
            big, w2l, b2l, x, y, NROWS, DD, FFD, FFD, DD, DD);

        ln_kernel<<<NROWS, 256, 0, stream>>>(y, ln2_g + (long)l * DD, ln2_b + (long)l * DD, x);
    }

    // final: out = x @ emb^T
    gemm128_kernel<true, false, false, false><<<dim3(8, 32), 256, 0, stream>>>(
        x, emb, nullptr, nullptr, out, NROWS, VV, DD, DD, DD, VV);
}

// Round 5
// 4453.703 us; speedup vs baseline: 1.5841x; 1.4057x over previous
//
#include <hip/hip_runtime.h>
#include <math.h>

// Dims (fixed by the problem)
#define BB 8
#define SS 512
#define DD 512
#define HH 8
#define HSD 64
#define FFD 2048
#define LL 6
#define VV 1024
#define NROWS (BB*SS)          // 4096
#define EPS 1e-5f

// ---------------------------------------------------------------------------
// Embed (unchanged — passing config)
// ---------------------------------------------------------------------------
__global__ __launch_bounds__(256)
void embed_kernel(const float* __restrict__ tokens,
                  const float* __restrict__ emb,
                  float* __restrict__ x)
{
    const int n = blockIdx.x;            // 0..4095
    const int s = n & (SS - 1);
    const int t = threadIdx.x;
    __shared__ int sidx;
    #pragma unroll
    for (int r = 0; r < 4; ++r) {
        int v = t + 256 * r;
        if (tokens[(long)n * VV + v] > 0.5f) sidx = v;
    }
    __syncthreads();
    const int idx = sidx;
    const float sq = 22.62741699796952f; // sqrt(512)
    #pragma unroll
    for (int r = 0; r < 2; ++r) {
        int d = t + 256 * r;
        float e = emb[(long)idx * DD + d] * sq;
        float expo  = (2.0f * (float)d) / 512.0f;
        float denom = powf(10000.0f, expo);
        float val   = (float)s / denom;
        float pe = ((d & 1) == 0) ? sinf(val) : cosf(val);
        x[(long)n * DD + d] = e + pe;
    }
}

// ---------------------------------------------------------------------------
// Tiled GEMM: 128 x TNB tiles, BK=16, 256 threads, 8 x (TNB/16) microtile.
// Per-element accumulation is a single sequential-k fmac chain -> BITWISE
// identical C regardless of TNB/BT/QKVB (winner-selection-critical attention
// logits depend on upstream bits).
// QKVB: B is qkv_w [H][D][192]; global col c maps to head c/192, col c%192.
// ---------------------------------------------------------------------------
template<int TNB, bool BT, bool QKVB, bool BIAS, bool RELU, bool RES>
__global__ __launch_bounds__(256)
void gemm_t(const float* __restrict__ A, const float* __restrict__ B,
            const float* __restrict__ bias, const float* __restrict__ res,
            float* __restrict__ C,
            int M, int N, int K, int lda, int ldb, int ldc)
{
    constexpr int NW  = TNB / 16;          // cols per thread
    constexpr int P   = TNB / 64;          // B-staging passes
    constexpr int BSH = (TNB == 128) ? 5 : 4;
    const int t  = threadIdx.x;
    const int bm = blockIdx.y * 128;
    const int bn = blockIdx.x * TNB;
    __shared__ float As[16][132];
    __shared__ float Bs[16][TNB + 4];
    const int tx = t & 15;                 // col group (tx*NW)
    const int ty = t >> 4;                 // row group (ty*8)
    float acc[8][NW] = {};

    for (int k0 = 0; k0 < K; k0 += 16) {
        #pragma unroll
        for (int p = 0; p < 2; ++p) {      // A: 128x16 -> As[k][m] transposed
            int q = t + 256 * p;
            int r = q >> 2, kc = (q & 3) * 4;
            float4 a4 = *(const float4*)(A + (long)(bm + r) * lda + k0 + kc);
            As[kc + 0][r] = a4.x; As[kc + 1][r] = a4.y;
            As[kc + 2][r] = a4.z; As[kc + 3][r] = a4.w;
        }
        if (QKVB) {
            #pragma unroll
            for (int p = 0; p < P; ++p) {  // B: per-head remap, row-major tile
                int q = t + 256 * p;
                int r = q >> BSH, c = (q & ((1 << BSH) - 1)) * 4;
                int col = bn + c;
                int h = (int)((unsigned)col / 192u);
                int j = col - h * 192;
                *(float4*)&Bs[r][c] =
                    *(const float4*)(B + (long)h * (DD * 192) + (long)(k0 + r) * 192 + j);
            }
        } else if (!BT) {
            #pragma unroll
            for (int p = 0; p < P; ++p) {  // B: 16xTNB row-major
                int q = t + 256 * p;
                int r = q >> BSH, c = (q & ((1 << BSH) - 1)) * 4;
                *(float4*)&Bs[r][c] = *(const float4*)(B + (long)(k0 + r) * ldb + bn + c);
            }
        } else {
            #pragma unroll
            for (int p = 0; p < P; ++p) {  // B^T: TNB rows x 16 k -> Bs[k][n]
                int q = t + 256 * p;
                int r = q >> 2, kc = (q & 3) * 4;
                float4 b4 = *(const float4*)(B + (long)(bn + r) * ldb + k0 + kc);
                Bs[kc + 0][r] = b4.x; Bs[kc + 1][r] = b4.y;
                Bs[kc + 2][r] = b4.z; Bs[kc + 3][r] = b4.w;
            }
        }
        __syncthreads();
        #pragma unroll
        for (int kk = 0; kk < 16; ++kk) {
            float a[8], bv[NW];
            *(float4*)&a[0] = *(const float4*)&As[kk][ty * 8];
            *(float4*)&a[4] = *(const float4*)&As[kk][ty * 8 + 4];
            #pragma unroll
            for (int g = 0; g < NW / 4; ++g)
                *(float4*)&bv[g * 4] = *(const float4*)&Bs[kk][tx * NW + g * 4];
            #pragma unroll
            for (int ii = 0; ii < 8; ++ii)
                #pragma unroll
                for (int jj = 0; jj < NW; ++jj)
                    acc[ii][jj] += a[ii] * bv[jj];
        }
        __syncthreads();
    }

    #pragma unroll
    for (int ii = 0; ii < 8; ++ii) {
        int r = bm + ty * 8 + ii;
        #pragma unroll
        for (int jj = 0; jj < NW; ++jj) {
            int c = bn + tx * NW + jj;
            float v = acc[ii][jj];
            if (BIAS) v += bias[c];
            if (RELU) v = fmaxf(v, 0.0f);
            if (RES)  v += res[(long)r * ldc + c];
            C[(long)r * ldc + c] = v;
        }
    }
}

// ---------------------------------------------------------------------------
// Attention: exact softmax, math bitwise-identical to the passing R4 kernel
// (dot expression, j->lane mapping, butterflies, P normalization, sequential-j
// PV chain all preserved). Changes are execution-only:
//  - K/V tiles use row stride 65 (65%32==1 -> full bank spread; 2-way is free)
//    with scalar LDS accesses (was stride 68 -> 8-way conflicts, 1.37e8 cyc).
//  - LDS 53.5 KB -> 3 blocks/CU (was 54.8 KB -> 2).
// qkv layout: [n][h][192] (q:0..63,k:64..127,v:128..191), row stride 1536.
// ---------------------------------------------------------------------------
__global__ __launch_bounds__(256)
void attn_kernel(const float* __restrict__ qkv, float* __restrict__ oc)
{
    const int i0 = blockIdx.x * 16;
    const int h  = blockIdx.y, b = blockIdx.z;
    const int t  = threadIdx.x;
    const int w  = t >> 6;               // wave 0..3 -> rows 4w..4w+3
    const int ln = t & 63;               // lane -> j offset / output d

    __shared__ float Qs[16][64];         // Q rows (reads are broadcast)
    __shared__ float KVs[64][65];        // K tile (pass1) / V^T tile (pass2)
    __shared__ float Zb[16][512];        // z, then P

    const long bhBase = (long)b * SS * 1536 + (long)h * 192;

    {   // stage Q: 16 rows x 64, one float4/thread
        int r = t >> 4, c = (t & 15) * 4;
        *(float4*)&Qs[r][c] =
            *(const float4*)(qkv + bhBase + (long)(i0 + r) * 1536 + c);
    }
    __syncthreads();

    // ---- pass 1: scores ----
    for (int kt = 0; kt < 8; ++kt) {
        const int j0 = kt * 64;
        #pragma unroll
        for (int p = 0; p < 4; ++p) {    // K tile 64x64 row-major, stride 65
            int q = t + 256 * p;         // 0..1023
            int r = q >> 4, c = (q & 15) * 4;
            float4 k4 = *(const float4*)(qkv + bhBase + (long)(j0 + r) * 1536 + 64 + c);
            KVs[r][c + 0] = k4.x; KVs[r][c + 1] = k4.y;
            KVs[r][c + 2] = k4.z; KVs[r][c + 3] = k4.w;
        }
        __syncthreads();

        const float* krow = &KVs[ln][0];
        #pragma unroll
        for (int c = 0; c < 4; ++c) {
            const int i = 4 * w + c;
            const float4* q4 = (const float4*)&Qs[i][0];
            float dot = 0.0f;
            #pragma unroll
            for (int kk = 0; kk < 16; ++kk) {
                float4 qq = q4[kk];
                float kv0 = krow[kk * 4 + 0], kv1 = krow[kk * 4 + 1];
                float kv2 = krow[kk * 4 + 2], kv3 = krow[kk * 4 + 3];
                dot += qq.x * kv0 + qq.y * kv1 + qq.z * kv2 + qq.w * kv3;
            }
            const int gi = i0 + i, gj = j0 + ln;
            Zb[i][j0 + ln] = (gj <= gi) ? 0.0f : (dot * -1.0e6f) * 0.125f;
        }
        __syncthreads();
    }

    // ---- softmax (each wave: its 4 rows; verbatim reductions) ----
    #pragma unroll
    for (int c = 0; c < 4; ++c) {
        const int i = 4 * w + c;
        float p[8];
        float mx = -3.4e38f;
        #pragma unroll
        for (int r = 0; r < 8; ++r) { p[r] = Zb[i][r * 64 + ln]; mx = fmaxf(mx, p[r]); }
        #pragma unroll
        for (int o = 32; o >= 1; o >>= 1) mx = fmaxf(mx, __shfl_xor(mx, o));
        float sum = 0.0f;
        #pragma unroll
        for (int r = 0; r < 8; ++r) { p[r] = expf(p[r] - mx); sum += p[r]; }
        #pragma unroll
        for (int o = 32; o >= 1; o >>= 1) sum += __shfl_xor(sum, o);
        const float inv = 1.0f / sum;
        #pragma unroll
        for (int r = 0; r < 8; ++r) Zb[i][r * 64 + ln] = p[r] * inv;
    }
    __syncthreads();

    // ---- pass 2: O = P V, sequential-j fmac chain ----
    float oA[4] = {0.0f, 0.0f, 0.0f, 0.0f};
    for (int kt = 0; kt < 8; ++kt) {
        const int j0 = kt * 64;
        #pragma unroll
        for (int p = 0; p < 4; ++p) {    // V staged TRANSPOSED: KVs[d][j], stride 65
            int q = t + 256 * p;
            int r = q >> 4, c = (q & 15) * 4;
            float4 v4 = *(const float4*)(qkv + bhBase + (long)(j0 + r) * 1536 + 128 + c);
            KVs[c + 0][r] = v4.x; KVs[c + 1][r] = v4.y;
            KVs[c + 2][r] = v4.z; KVs[c + 3][r] = v4.w;
        }
        __syncthreads();

        const float* vt = &KVs[ln][0];   // V^T row d=ln
        #pragma unroll
        for (int c = 0; c < 4; ++c) {
            const int i = 4 * w + c;
            const float4* pr = (const float4*)&Zb[i][j0];
            float acc = oA[c];
            #pragma unroll
            for (int kk = 0; kk < 16; ++kk) {
                float4 pv = pr[kk];
                float vv0 = vt[kk * 4 + 0], vv1 = vt[kk * 4 + 1];
                float vv2 = vt[kk * 4 + 2], vv3 = vt[kk * 4 + 3];
                acc += pv.x * vv0;
                acc += pv.y * vv1;
                acc += pv.z * vv2;
                acc += pv.w * vv3;
            }
            oA[c] = acc;
        }
        __syncthreads();
    }

    // epilogue: concat-head layout oc[n][h*64 + d], d = lane (coalesced)
    #pragma unroll
    for (int c = 0; c < 4; ++c) {
        const int gi = i0 + 4 * w + c;
        oc[(long)(b * SS + gi) * DD + h * HSD + ln] = oA[c];
    }
}

// ---------------------------------------------------------------------------
// LayerNorm (unchanged)
// ---------------------------------------------------------------------------
__device__ __forceinline__ float blk_sum(float v, float* sb)
{
    #pragma unroll
    for (int m = 32; m >= 1; m >>= 1) v += __shfl_xor(v, m);
    if ((threadIdx.x & 63) == 0) sb[threadIdx.x >> 6] = v;
    __syncthreads();
    v = sb[0] + sb[1] + sb[2] + sb[3];
    __syncthreads();
    return v;
}

__global__ __launch_bounds__(256)
void ln_kernel(const float* __restrict__ in, const float* __restrict__ g,
               const float* __restrict__ bb, float* __restrict__ out)
{
    __shared__ float sb[4];
    const int n = blockIdx.x;
    const int t = threadIdx.x;
    const float* x = in + (long)n * DD;
    float v0 = x[t], v1 = x[t + 256];
    float total = blk_sum(v0 + v1, sb);
    float mean = total * (1.0f / 512.0f);
    float d0 = v0 - mean, d1 = v1 - mean;
    float ss = blk_sum(d0 * d0 + d1 * d1, sb);
    float var = ss * (1.0f / 512.0f);
    float inv = 1.0f / sqrtf(var + EPS);
    out[(long)n * DD + t]       = d0 * inv * g[t]       + bb[t];
    out[(long)n * DD + t + 256] = d1 * inv * g[t + 256] + bb[t + 256];
}

// ---------------------------------------------------------------------------
extern "C" void kernel_launch(void* const* d_in, const int* in_sizes, int n_in,
                              void* d_out, int out_size, void* d_ws, size_t ws_size,
                              hipStream_t stream)
{
    const float* tokens = (const float*)d_in[0];
    const float* emb    = (const float*)d_in[1];
    const float* qkv_w  = (const float*)d_in[2];
    const float* qkv_b  = (const float*)d_in[3];
    const float* out_w  = (const float*)d_in[4];
    const float* out_b  = (const float*)d_in[5];
    const float* w1     = (const float*)d_in[6];
    const float* b1     = (const float*)d_in[7];
    const float* w2     = (const float*)d_in[8];
    const float* b2     = (const float*)d_in[9];
    const float* ln1_g  = (const float*)d_in[10];
    const float* ln1_b  = (const float*)d_in[11];
    const float* ln2_g  = (const float*)d_in[12];
    const float* ln2_b  = (const float*)d_in[13];
    float* out = (float*)d_out;

    float* ws  = (float*)d_ws;
    float* x   = ws;                          // [4096,512]
    float* y   = x  + (long)NROWS * DD;       // [4096,512]
    float* oc  = y  + (long)NROWS * DD;       // [4096,512]
    float* big = oc + (long)NROWS * DD;       // [4096,2048]

    embed_kernel<<<NROWS, 256, 0, stream>>>(tokens, emb, x);

    for (int l = 0; l < LL; ++l) {
        const float* qw  = qkv_w + (long)l * HH * DD * 192;
        const float* qb  = qkv_b + (long)l * HH * 192;
        const float* ow  = out_w + (long)l * DD * DD;
        const float* ob  = out_b + (long)l * DD;
        const float* w1l = w1 + (long)l * DD * FFD;
        const float* b1l = b1 + (long)l * FFD;
        const float* w2l = w2 + (long)l * FFD * DD;
        const float* b2l = b2 + (long)l * DD;

        // QKV: [4096,512] @ per-head-remapped [512,1536] -> big (ldc=1536)
        gemm_t<64, false, true, true, false, false><<<dim3(24, 32), 256, 0, stream>>>(
            x, qw, qb, nullptr, big, NROWS, 1536, DD, DD, 192, 1536);

        attn_kernel<<<dim3(SS / 16, HH, BB), 256, 0, stream>>>(big, oc);

        // out-proj + bias + residual(x) -> y   (N=512 -> TN=64, 256 blocks)
        gemm_t<64, false, false, true, false, true><<<dim3(8, 32), 256, 0, stream>>>(
            oc, ow, ob, x, y, NROWS, DD, DD, DD, DD, DD);

        ln_kernel<<<NROWS, 256, 0, stream>>>(y, ln1_g + (long)l * DD, ln1_b + (long)l * DD, x);

        // FFN1 + relu -> big   (N=2048 -> TN=128, 512 blocks)
        gemm_t<128, false, false, true, true, false><<<dim3(16, 32), 256, 0, stream>>>(
            x, w1l, b1l, nullptr, big, NROWS, FFD, DD, DD, FFD, FFD);

        // FFN2 + bias + residual(x) -> y   (N=512 -> TN=64, 256 blocks)
        gemm_t<64, false, false, true, false, true><<<dim3(8, 32), 256, 0, stream>>>(
            big, w2l, b2l, x, y, NROWS, DD, FFD, FFD, DD, DD);

        ln_kernel<<<NROWS, 256, 0, stream>>>(y, ln2_g + (long)l * DD, ln2_b + (long)l * DD, x);
    }

    // final: out = x @ emb^T   (N=1024 -> TN=64, 512 blocks)
    gemm_t<64, true, false, false, false, false><<<dim3(16, 32), 256, 0, stream>>>(
        x, emb, nullptr, nullptr, out, NROWS, VV, DD, DD, DD, VV);
}

// Round 6
// 4158.131 us; speedup vs baseline: 1.6967x; 1.0711x over previous
//
#include <hip/hip_runtime.h>
#include <math.h>

// Dims (fixed by the problem)
#define BB 8
#define SS 512
#define DD 512
#define HH 8
#define HSD 64
#define FFD 2048
#define LL 6
#define VV 1024
#define NROWS (BB*SS)          // 4096
#define EPS 1e-5f

// ---------------------------------------------------------------------------
// Embed (unchanged — passing config)
// ---------------------------------------------------------------------------
__global__ __launch_bounds__(256)
void embed_kernel(const float* __restrict__ tokens,
                  const float* __restrict__ emb,
                  float* __restrict__ x)
{
    const int n = blockIdx.x;            // 0..4095
    const int s = n & (SS - 1);
    const int t = threadIdx.x;
    __shared__ int sidx;
    #pragma unroll
    for (int r = 0; r < 4; ++r) {
        int v = t + 256 * r;
        if (tokens[(long)n * VV + v] > 0.5f) sidx = v;
    }
    __syncthreads();
    const int idx = sidx;
    const float sq = 22.62741699796952f; // sqrt(512)
    #pragma unroll
    for (int r = 0; r < 2; ++r) {
        int d = t + 256 * r;
        float e = emb[(long)idx * DD + d] * sq;
        float expo  = (2.0f * (float)d) / 512.0f;
        float denom = powf(10000.0f, expo);
        float val   = (float)s / denom;
        float pe = ((d & 1) == 0) ? sinf(val) : cosf(val);
        x[(long)n * DD + d] = e + pe;
    }
}

// ---------------------------------------------------------------------------
// Tiled GEMM: 128 x TNB tiles, BK=32 (staging-only change vs BK=16 — the
// per-element accumulation stays ONE sequential-k fmac chain -> bitwise
// identical C; winner-selection-critical attention logits depend on bits).
// QKVB: B is qkv_w [H][D][192]; global col c maps to head c/192, col c%192.
// ---------------------------------------------------------------------------
template<int TNB, bool BT, bool QKVB, bool BIAS, bool RELU, bool RES>
__global__ __launch_bounds__(256)
void gemm_t(const float* __restrict__ A, const float* __restrict__ B,
            const float* __restrict__ bias, const float* __restrict__ res,
            float* __restrict__ C,
            int M, int N, int K, int lda, int ldb, int ldc)
{
    constexpr int NW  = TNB / 16;          // cols per thread
    constexpr int BSH = (TNB == 128) ? 5 : 4;
    const int t  = threadIdx.x;
    const int bm = blockIdx.y * 128;
    const int bn = blockIdx.x * TNB;
    __shared__ float As[32][132];
    __shared__ float Bs[32][TNB + 4];
    const int tx = t & 15;                 // col group (tx*NW)
    const int ty = t >> 4;                 // row group (ty*8)
    float acc[8][NW] = {};

    for (int k0 = 0; k0 < K; k0 += 32) {
        #pragma unroll
        for (int p = 0; p < 4; ++p) {      // A: 128x32 -> As[k][m] transposed
            int q = t + 256 * p;           // 0..1023
            int r = q >> 3, kc = (q & 7) * 4;
            float4 a4 = *(const float4*)(A + (long)(bm + r) * lda + k0 + kc);
            As[kc + 0][r] = a4.x; As[kc + 1][r] = a4.y;
            As[kc + 2][r] = a4.z; As[kc + 3][r] = a4.w;
        }
        if (QKVB) {
            #pragma unroll
            for (int p = 0; p < TNB / 32; ++p) {  // B: per-head remap, row-major
                int q = t + 256 * p;
                int r = q >> BSH, c = (q & ((1 << BSH) - 1)) * 4;
                int col = bn + c;
                int h = (int)((unsigned)col / 192u);
                int j = col - h * 192;
                *(float4*)&Bs[r][c] =
                    *(const float4*)(B + (long)h * (DD * 192) + (long)(k0 + r) * 192 + j);
            }
        } else if (!BT) {
            #pragma unroll
            for (int p = 0; p < TNB / 32; ++p) {  // B: 32xTNB row-major
                int q = t + 256 * p;
                int r = q >> BSH, c = (q & ((1 << BSH) - 1)) * 4;
                *(float4*)&Bs[r][c] = *(const float4*)(B + (long)(k0 + r) * ldb + bn + c);
            }
        } else {
            #pragma unroll
            for (int p = 0; p < TNB / 32; ++p) {  // B^T: TNB rows x 32 k -> Bs[k][n]
                int q = t + 256 * p;
                int r = q >> 3, kc = (q & 7) * 4;
                float4 b4 = *(const float4*)(B + (long)(bn + r) * ldb + k0 + kc);
                Bs[kc + 0][r] = b4.x; Bs[kc + 1][r] = b4.y;
                Bs[kc + 2][r] = b4.z; Bs[kc + 3][r] = b4.w;
            }
        }
        __syncthreads();
        #pragma unroll
        for (int kk = 0; kk < 32; ++kk) {
            float a[8], bv[NW];
            *(float4*)&a[0] = *(const float4*)&As[kk][ty * 8];
            *(float4*)&a[4] = *(const float4*)&As[kk][ty * 8 + 4];
            #pragma unroll
            for (int g = 0; g < NW / 4; ++g)
                *(float4*)&bv[g * 4] = *(const float4*)&Bs[kk][tx * NW + g * 4];
            #pragma unroll
            for (int ii = 0; ii < 8; ++ii)
                #pragma unroll
                for (int jj = 0; jj < NW; ++jj)
                    acc[ii][jj] += a[ii] * bv[jj];
        }
        __syncthreads();
    }

    #pragma unroll
    for (int ii = 0; ii < 8; ++ii) {
        int r = bm + ty * 8 + ii;
        #pragma unroll
        for (int jj = 0; jj < NW; ++jj) {
            int c = bn + tx * NW + jj;
            float v = acc[ii][jj];
            if (BIAS) v += bias[c];
            if (RELU) v = fmaxf(v, 0.0f);
            if (RES)  v += res[(long)r * ldc + c];
            C[(long)r * ldc + c] = v;
        }
    }
}

// ---------------------------------------------------------------------------
// Attention: exact softmax; FP expression trees byte-identical to the passing
// R1/R4/R5 kernels. Execution change only: K / V^T tiles live in an
// XOR-swizzled flat LDS array (4-dword-group swizzle) so per-lane row reads
// are conflict-free ds_read_b128, and each lane register-caches its 64 K
// (resp. V^T) values once per tile, reused across its 4 rows.
// qkv layout: [n][h][192] (q:0..63,k:64..127,v:128..191), row stride 1536.
// ---------------------------------------------------------------------------
__device__ __forceinline__ int swz(int row, int col)
{   // swizzle on 4-dword groups; rows stay 16B-aligned
    return row * 64 + ((col & ~3) ^ ((row & 15) * 4)) + (col & 3);
}

__global__ __launch_bounds__(256)
void attn_kernel(const float* __restrict__ qkv, float* __restrict__ oc)
{
    const int i0 = blockIdx.x * 16;
    const int h  = blockIdx.y, b = blockIdx.z;
    const int t  = threadIdx.x;
    const int w  = t >> 6;               // wave 0..3 -> rows 4w..4w+3
    const int ln = t & 63;               // lane -> j offset / output d

    __shared__ float Qs[16][64];                   // Q rows (broadcast reads)
    __shared__ __align__(16) float KV[64 * 64];    // swizzled K / V^T tile
    __shared__ float Zb[16][512];                  // z, then P

    const long bhBase = (long)b * SS * 1536 + (long)h * 192;

    {   // stage Q: 16 rows x 64, one float4/thread
        int r = t >> 4, c = (t & 15) * 4;
        *(float4*)&Qs[r][c] =
            *(const float4*)(qkv + bhBase + (long)(i0 + r) * 1536 + c);
    }
    __syncthreads();

    // ---- pass 1: scores ----
    for (int kt = 0; kt < 8; ++kt) {
        const int j0 = kt * 64;
        #pragma unroll
        for (int p = 0; p < 4; ++p) {    // K tile 64x64, swizzled float4 writes
            int q = t + 256 * p;         // 0..1023
            int r = q >> 4, c = (q & 15) * 4;
            float4 k4 = *(const float4*)(qkv + bhBase + (long)(j0 + r) * 1536 + 64 + c);
            *(float4*)&KV[swz(r, c)] = k4;
        }
        __syncthreads();

        float4 kreg[16];
        #pragma unroll
        for (int kk = 0; kk < 16; ++kk)
            kreg[kk] = *(const float4*)&KV[swz(ln, kk * 4)];

        #pragma unroll
        for (int c = 0; c < 4; ++c) {
            const int i = 4 * w + c;
            const float4* q4 = (const float4*)&Qs[i][0];
            float dot = 0.0f;
            #pragma unroll
            for (int kk = 0; kk < 16; ++kk) {
                float4 kv = kreg[kk];
                float4 qq = q4[kk];
                dot += qq.x * kv.x + qq.y * kv.y + qq.z * kv.z + qq.w * kv.w;
            }
            const int gi = i0 + i, gj = j0 + ln;
            Zb[i][j0 + ln] = (gj <= gi) ? 0.0f : (dot * -1.0e6f) * 0.125f;
        }
        __syncthreads();
    }

    // ---- softmax (each wave: its 4 rows; verbatim reductions) ----
    #pragma unroll
    for (int c = 0; c < 4; ++c) {
        const int i = 4 * w + c;
        float p[8];
        float mx = -3.4e38f;
        #pragma unroll
        for (int r = 0; r < 8; ++r) { p[r] = Zb[i][r * 64 + ln]; mx = fmaxf(mx, p[r]); }
        #pragma unroll
        for (int o = 32; o >= 1; o >>= 1) mx = fmaxf(mx, __shfl_xor(mx, o));
        float sum = 0.0f;
        #pragma unroll
        for (int r = 0; r < 8; ++r) { p[r] = expf(p[r] - mx); sum += p[r]; }
        #pragma unroll
        for (int o = 32; o >= 1; o >>= 1) sum += __shfl_xor(sum, o);
        const float inv = 1.0f / sum;
        #pragma unroll
        for (int r = 0; r < 8; ++r) Zb[i][r * 64 + ln] = p[r] * inv;
    }
    __syncthreads();

    // ---- pass 2: O = P V, sequential-j fmac chain (verbatim statements) ----
    float oA[4] = {0.0f, 0.0f, 0.0f, 0.0f};
    for (int kt = 0; kt < 8; ++kt) {
        const int j0 = kt * 64;
        #pragma unroll
        for (int p = 0; p < 4; ++p) {    // V staged TRANSPOSED into swizzled KV
            int q = t + 256 * p;
            int r = q >> 4, c = (q & 15) * 4;    // r = j, c = d base
            float4 v4 = *(const float4*)(qkv + bhBase + (long)(j0 + r) * 1536 + 128 + c);
            KV[swz(c + 0, r)] = v4.x;
            KV[swz(c + 1, r)] = v4.y;
            KV[swz(c + 2, r)] = v4.z;
            KV[swz(c + 3, r)] = v4.w;
        }
        __syncthreads();

        float4 vreg[16];
        #pragma unroll
        for (int kk = 0; kk < 16; ++kk)
            vreg[kk] = *(const float4*)&KV[swz(ln, kk * 4)];

        #pragma unroll
        for (int c = 0; c < 4; ++c) {
            const int i = 4 * w + c;
            const float4* pr = (const float4*)&Zb[i][j0];
            float acc = oA[c];
            #pragma unroll
            for (int kk = 0; kk < 16; ++kk) {
                float4 pv = pr[kk];
                float4 vv = vreg[kk];
                acc += pv.x * vv.x;
                acc += pv.y * vv.y;
                acc += pv.z * vv.z;
                acc += pv.w * vv.w;
            }
            oA[c] = acc;
        }
        __syncthreads();
    }

    // epilogue: concat-head layout oc[n][h*64 + d], d = lane (coalesced)
    #pragma unroll
    for (int c = 0; c < 4; ++c) {
        const int gi = i0 + 4 * w + c;
        oc[(long)(b * SS + gi) * DD + h * HSD + ln] = oA[c];
    }
}

// ---------------------------------------------------------------------------
// LayerNorm (unchanged)
// ---------------------------------------------------------------------------
__device__ __forceinline__ float blk_sum(float v, float* sb)
{
    #pragma unroll
    for (int m = 32; m >= 1; m >>= 1) v += __shfl_xor(v, m);
    if ((threadIdx.x & 63) == 0) sb[threadIdx.x >> 6] = v;
    __syncthreads();
    v = sb[0] + sb[1] + sb[2] + sb[3];
    __syncthreads();
    return v;
}

__global__ __launch_bounds__(256)
void ln_kernel(const float* __restrict__ in, const float* __restrict__ g,
               const float* __restrict__ bb, float* __restrict__ out)
{
    __shared__ float sb[4];
    const int n = blockIdx.x;
    const int t = threadIdx.x;
    const float* x = in + (long)n * DD;
    float v0 = x[t], v1 = x[t + 256];
    float total = blk_sum(v0 + v1, sb);
    float mean = total * (1.0f / 512.0f);
    float d0 = v0 - mean, d1 = v1 - mean;
    float ss = blk_sum(d0 * d0 + d1 * d1, sb);
    float var = ss * (1.0f / 512.0f);
    float inv = 1.0f / sqrtf(var + EPS);
    out[(long)n * DD + t]       = d0 * inv * g[t]       + bb[t];
    out[(long)n * DD + t + 256] = d1 * inv * g[t + 256] + bb[t + 256];
}

// ---------------------------------------------------------------------------
extern "C" void kernel_launch(void* const* d_in, const int* in_sizes, int n_in,
                              void* d_out, int out_size, void* d_ws, size_t ws_size,
                              hipStream_t stream)
{
    const float* tokens = (const float*)d_in[0];
    const float* emb    = (const float*)d_in[1];
    const float* qkv_w  = (const float*)d_in[2];
    const float* qkv_b  = (const float*)d_in[3];
    const float* out_w  = (const float*)d_in[4];
    const float* out_b  = (const float*)d_in[5];
    const float* w1     = (const float*)d_in[6];
    const float* b1     = (const float*)d_in[7];
    const float* w2     = (const float*)d_in[8];
    const float* b2     = (const float*)d_in[9];
    const float* ln1_g  = (const float*)d_in[10];
    const float* ln1_b  = (const float*)d_in[11];
    const float* ln2_g  = (const float*)d_in[12];
    const float* ln2_b  = (const float*)d_in[13];
    float* out = (float*)d_out;

    float* ws  = (float*)d_ws;
    float* x   = ws;                          // [4096,512]
    float* y   = x  + (long)NROWS * DD;       // [4096,512]
    float* oc  = y  + (long)NROWS * DD;       // [4096,512]
    float* big = oc + (long)NROWS * DD;       // [4096,2048]

    embed_kernel<<<NROWS, 256, 0, stream>>>(tokens, emb, x);

    for (int l = 0; l < LL; ++l) {
        const float* qw  = qkv_w + (long)l * HH * DD * 192;
        const float* qb  = qkv_b + (long)l * HH * 192;
        const float* ow  = out_w + (long)l * DD * DD;
        const float* ob  = out_b + (long)l * DD;
        const float* w1l = w1 + (long)l * DD * FFD;
        const float* b1l = b1 + (long)l * FFD;
        const float* w2l = w2 + (long)l * FFD * DD;
        const float* b2l = b2 + (long)l * DD;

        // QKV: [4096,512] @ per-head-remapped [512,1536] -> big (ldc=1536)
        gemm_t<64, false, true, true, false, false><<<dim3(24, 32), 256, 0, stream>>>(
            x, qw, qb, nullptr, big, NROWS, 1536, DD, DD, 192, 1536);

        attn_kernel<<<dim3(SS / 16, HH, BB), 256, 0, stream>>>(big, oc);

        // out-proj + bias + residual(x) -> y
        gemm_t<64, false, false, true, false, true><<<dim3(8, 32), 256, 0, stream>>>(
            oc, ow, ob, x, y, NROWS, DD, DD, DD, DD, DD);

        ln_kernel<<<NROWS, 256, 0, stream>>>(y, ln1_g + (long)l * DD, ln1_b + (long)l * DD, x);

        // FFN1 + relu -> big
        gemm_t<128, false, false, true, true, false><<<dim3(16, 32), 256, 0, stream>>>(
            x, w1l, b1l, nullptr, big, NROWS, FFD, DD, DD, FFD, FFD);

        // FFN2 + bias + residual(x) -> y
        gemm_t<64, false, false, true, false, true><<<dim3(8, 32), 256, 0, stream>>>(
            big, w2l, b2l, x, y, NROWS, DD, FFD, FFD, DD, DD);

        ln_kernel<<<NROWS, 256, 0, stream>>>(y, ln2_g + (long)l * DD, ln2_b + (long)l * DD, x);
    }

    // final: out = x @ emb^T
    gemm_t<64, true, false, false, false, false><<<dim3(16, 32), 256, 0, stream>>>(
        x, emb, nullptr, nullptr, out, NROWS, VV, DD, DD, DD, VV);
}